// Round 15
// baseline (115.264 us; speedup 1.0000x reference)
//
#include <hip/hip_runtime.h>
#include <hip/hip_bf16.h>

#define B_ 2
#define T_ 2048
#define C_ 1024
#define H_ 16
#define D_ 64

typedef __attribute__((ext_vector_type(8))) short bf16x8;   // MFMA A/B operand (8 bf16)
typedef __attribute__((ext_vector_type(4))) float f32x4;    // MFMA C/D
typedef __attribute__((ext_vector_type(8))) unsigned short u16x8;
typedef __attribute__((ext_vector_type(2))) unsigned int u32x2;
typedef __attribute__((ext_vector_type(4))) unsigned int u32x4;

__device__ __forceinline__ unsigned short bf1(float a) {
    __bf16 x = (__bf16)a;
    return __builtin_bit_cast(unsigned short, x);
}
__device__ __forceinline__ unsigned int pk2(float a, float b) {
    return (unsigned int)bf1(a) | ((unsigned int)bf1(b) << 16);
}
__device__ __forceinline__ float bf2f(unsigned short u) {
    union { unsigned int u; float f; } v; v.u = (unsigned int)u << 16;
    return v.f;
}

__device__ __forceinline__ void gll16(const void* g, void* l) {
    __builtin_amdgcn_global_load_lds(
        (const __attribute__((address_space(1))) unsigned int*)g,
        (__attribute__((address_space(3))) unsigned int*)l, 16, 0, 0);
}

// counted vmcnt across raw barrier (T4): keep newest prefetch in flight
#define VM_WAIT4() asm volatile("s_waitcnt vmcnt(4)" ::: "memory")
#define VM_WAIT0() asm volatile("s_waitcnt vmcnt(0)" ::: "memory")

// ---------------------------------------------------------------------------
// Kernel 0: fused prep.  bid<1024: x f32->bf16 (xb). else: wq|wk|wv -> wb.
// ---------------------------------------------------------------------------
__global__ __launch_bounds__(256) void prep_all(
    const float* __restrict__ x, const float* __restrict__ wq,
    const float* __restrict__ wk, const float* __restrict__ wv,
    unsigned short* __restrict__ xb, unsigned short* __restrict__ wb)
{
    const int bid = blockIdx.x, tid = threadIdx.x;
    if (bid < 1024) {
        const size_t i = ((size_t)bid * 256 + tid) * 16;
        float4 f0 = *reinterpret_cast<const float4*>(x + i);
        float4 f1 = *reinterpret_cast<const float4*>(x + i + 4);
        float4 f2 = *reinterpret_cast<const float4*>(x + i + 8);
        float4 f3 = *reinterpret_cast<const float4*>(x + i + 12);
        u32x4 a = {pk2(f0.x, f0.y), pk2(f0.z, f0.w), pk2(f1.x, f1.y), pk2(f1.z, f1.w)};
        u32x4 b = {pk2(f2.x, f2.y), pk2(f2.z, f2.w), pk2(f3.x, f3.y), pk2(f3.z, f3.w)};
        *reinterpret_cast<u32x4*>(xb + i) = a;
        *reinterpret_cast<u32x4*>(xb + i + 8) = b;
    } else {
        const int rb = (bid - 1024) * 4;
        const float* src = (rb < 1024) ? wq + (size_t)rb * 1024
                         : (rb < 2048) ? wk + (size_t)(rb - 1024) * 1024
                                       : wv + (size_t)(rb - 2048) * 1024;
        const float sc = (rb < 1024) ? 0.125f * 1.4426950408889634f : 1.0f;
        const float4* s4 = (const float4*)src;
        u32x2* d = (u32x2*)(wb + (size_t)rb * 1024);
#pragma unroll
        for (int k = 0; k < 4; k++) {
            float4 v = s4[k * 256 + tid];
            u32x2 w;
            w[0] = pk2(v.x * sc, v.y * sc);
            w[1] = pk2(v.z * sc, v.w * sc);
            d[k * 256 + tid] = w;
        }
    }
}

// ---------------------------------------------------------------------------
// Kernel 1: qkv GEMM.  Z[4096,3072] = xb[4096,1024](bf16) * wb^T(bf16)
// 3-buffer, 2-deep prefetch, counted vmcnt(4) across raw s_barrier (T3/T4).
// BK=32, 48KB LDS (3 blocks/CU). Q,K [b][h][t][d]; V transposed [b][h][d][t].
// ---------------------------------------------------------------------------
__global__ __launch_bounds__(256) void qkv_gemm(
    const unsigned short* __restrict__ xb, const unsigned short* __restrict__ wb,
    unsigned short* __restrict__ qkv)
{
    __shared__ __align__(16) unsigned short ABs[3][2][128 * 32];
    const int tid = threadIdx.x;
    const int lane = tid & 63, wave = tid >> 6;
    const int g = lane >> 4, c16 = lane & 15;
    const int xcd = blockIdx.x & 7, idx = blockIdx.x >> 3;
    const int bm = (xcd << 2) + idx / 24, bn = idx % 24;
    const int jbase = bn << 7;
    const int which = jbase >> 10;

    const int srow = lane >> 2, sch = (lane & 3) << 3;
    const unsigned short* asrc = xb + ((size_t)(bm << 7) + wave * 32 + srow) * C_ + sch;
    const unsigned short* bsrc = wb + ((size_t)(bn << 7) + wave * 32 + srow) * C_ + sch;

    f32x4 acc[4][4];
#pragma unroll
    for (int i = 0; i < 4; i++)
#pragma unroll
        for (int j = 0; j < 4; j++) acc[i][j] = (f32x4){0.f, 0.f, 0.f, 0.f};

    const int wm = (wave >> 1) << 6, wn = (wave & 1) << 6;

    auto stage = [&](int bi, int k0) {
        gll16(asrc + k0,           &ABs[bi][0][(wave * 32) << 5]);
        gll16(asrc + k0 + 16 * C_, &ABs[bi][0][(wave * 32 + 16) << 5]);
        gll16(bsrc + k0,           &ABs[bi][1][(wave * 32) << 5]);
        gll16(bsrc + k0 + 16 * C_, &ABs[bi][1][(wave * 32 + 16) << 5]);
    };

    stage(0, 0);
    stage(1, 32);
    int bi = 0;
    for (int t = 0; t < 32; ++t) {
        if (t < 31) { VM_WAIT4(); } else { VM_WAIT0(); }
        __builtin_amdgcn_s_barrier();
        if (t + 2 < 32) stage(bi + 2 >= 3 ? bi - 1 : bi + 2, (t + 2) << 5);

        const unsigned short* Ab = &ABs[bi][0][0];
        const unsigned short* Bb = &ABs[bi][1][0];
        bf16x8 af[4], bfv[4];
#pragma unroll
        for (int m = 0; m < 4; m++)
            af[m] = *reinterpret_cast<const bf16x8*>(&Ab[((wm + m * 16 + c16) << 5) + g * 8]);
#pragma unroll
        for (int n = 0; n < 4; n++)
            bfv[n] = *reinterpret_cast<const bf16x8*>(&Bb[((wn + n * 16 + c16) << 5) + g * 8]);
#pragma unroll
        for (int m = 0; m < 4; m++)
#pragma unroll
            for (int n = 0; n < 4; n++)
                acc[m][n] = __builtin_amdgcn_mfma_f32_16x16x32_bf16(af[m], bfv[n], acc[m][n], 0, 0, 0);
        bi = (bi + 1 == 3) ? 0 : bi + 1;
    }

    if (which < 2) {
#pragma unroll
        for (int m = 0; m < 4; m++) {
            const int grow = (bm << 7) + wm + m * 16 + (g << 2);
#pragma unroll
            for (int n = 0; n < 4; n++) {
                const int jj = (jbase + wn + n * 16 + c16) & 1023;
                const int h = jj >> 6, d = jj & 63;
#pragma unroll
                for (int r = 0; r < 4; r++) {
                    const int row = grow + r;
                    const int b = row >> 11, t = row & 2047;
                    const size_t off = ((size_t)((which * B_ + b) * H_ + h) * T_ + t) * 64 + d;
                    qkv[off] = bf1(acc[m][n][r]);
                }
            }
        }
    } else {
        // V transposed: vT[b][h][d][t]
#pragma unroll
        for (int m = 0; m < 4; m++) {
            const int grow = (bm << 7) + wm + m * 16 + (g << 2);
            const int b = grow >> 11, t = grow & 2047;
#pragma unroll
            for (int n = 0; n < 4; n++) {
                const int jj = (jbase + wn + n * 16 + c16) & 1023;
                const int h = jj >> 6, d = jj & 63;
                u32x2 w;
                w[0] = pk2(acc[m][n][0], acc[m][n][1]);
                w[1] = pk2(acc[m][n][2], acc[m][n][3]);
                const size_t off = ((size_t)((2 * B_ + b) * H_ + h) * 64 + d) * T_ + t;
                *reinterpret_cast<u32x2*>(&qkv[off]) = w;
            }
        }
    }
}

// ---------------------------------------------------------------------------
// Kernel 2: causal flash attention, STATIC-MAX softmax, QBLK=128.
// R13 decode (XCD-pinned, kv-split) + 3-buffer 2-deep counted-vmcnt pipeline:
// prefetched K/V loads stay in flight across TWO bodies before being waited.
// ---------------------------------------------------------------------------
__global__ __launch_bounds__(256) void attn(
    const unsigned short* __restrict__ qkv,
    unsigned short* __restrict__ opA, unsigned short* __restrict__ opB,
    float* __restrict__ lbuf)
{
    __shared__ __align__(16) unsigned short KV[3][2][64 * 64];   // [buf][K|V][tile]
    __shared__ __align__(16) unsigned short Ps[4][16 * 64];
    const int tid = threadIdx.x, lane = tid & 63, wave = tid >> 6;
    const int g = lane >> 4, c16 = lane & 15;
    const int xs = blockIdx.x & 7;
    const int inner = blockIdx.x >> 3;          // 0..127 within the XCD
    const int qt = 15 - (inner >> 3);           // longest first
    const int split = (inner >> 2) & 1;
    const int bh = (xs << 2) + (inner & 3);
    const int b = bh >> 4, h = bh & 15;
    const size_t headoff = (size_t)(b * H_ + h) * T_ * 64;
    const size_t QSZ = (size_t)B_ * H_ * T_ * 64;
    const unsigned short* qp = qkv + headoff;
    const unsigned short* kp = qkv + QSZ + headoff;
    const unsigned short* vTp = qkv + 2 * QSZ + headoff;   // [d][t]

    const int h1 = qt + 1;                      // kv tiles: [0, 2qt+2)
    const int itlo = split ? h1 : 0, ithi = split ? (2 * qt + 2) : h1;

    const int qb0 = (qt << 7) + wave * 16;      // q-half 0 wave base
    const int qb1 = qb0 + 64;                   // q-half 1 wave base
    bf16x8 qf00, qf01, qf10, qf11;
    {
        const size_t r0 = (size_t)(qb0 + c16) * 64;
        const size_t r1 = (size_t)(qb1 + c16) * 64;
        qf00 = *reinterpret_cast<const bf16x8*>(qp + r0 + g * 8);
        qf01 = *reinterpret_cast<const bf16x8*>(qp + r0 + 32 + g * 8);
        qf10 = *reinterpret_cast<const bf16x8*>(qp + r1 + g * 8);
        qf11 = *reinterpret_cast<const bf16x8*>(qp + r1 + 32 + g * 8);
    }

    const bf16x8 ones = {0x3F80, 0x3F80, 0x3F80, 0x3F80, 0x3F80, 0x3F80, 0x3F80, 0x3F80};
    f32x4 lac0 = (f32x4){0.f, 0.f, 0.f, 0.f}, lac1 = (f32x4){0.f, 0.f, 0.f, 0.f};
    f32x4 acc0[4], acc1[4];
#pragma unroll
    for (int i = 0; i < 4; i++) {
        acc0[i] = (f32x4){0.f, 0.f, 0.f, 0.f};
        acc1[i] = (f32x4){0.f, 0.f, 0.f, 0.f};
    }

    // ---- loop-invariant LDS read offsets ----
    const int sw = c16 & 7;
    const int rdo0 = (c16 << 6) + ((g ^ sw) << 3);         // chunk g
    const int rdo1 = (c16 << 6) + (((g + 4) ^ sw) << 3);   // chunk g+4
    const unsigned short* par0 = Ps[wave] + rdo0;
    const unsigned short* par1 = Ps[wave] + rdo1;
    unsigned short* pw[4];
#pragma unroll
    for (int f = 0; f < 4; f++)
        pw[f] = Ps[wave] + (c16 << 6)
              + (((((f << 1) + (g >> 1))) ^ sw) << 3) + ((g & 1) << 2);

    // ---- staging (pre-swizzled global source, linear LDS dest) ----
    const int srow8 = lane >> 3;
    const int swc = ((lane & 7) ^ srow8) << 3;
    const unsigned short* ksrc = kp + (size_t)(wave * 16 + srow8) * 64 + swc;
    const unsigned short* vsrc = vTp + (size_t)(wave * 16 + srow8) * T_ + swc;

    auto stageTo = [&](int bi, int s0) {
#pragma unroll
        for (int i = 0; i < 2; i++) {
            gll16(ksrc + (size_t)(s0 + i * 8) * 64, &KV[bi][0][(wave * 16 + i * 8) << 6]);
            gll16(vsrc + s0 + (size_t)i * 8 * T_, &KV[bi][1][(wave * 16 + i * 8) << 6]);
        }
    };

    auto body = [&](int bi, int it) {
        const int s0 = it << 6;
        const unsigned short* kb = &KV[bi][0][0];
        const unsigned short* vb = &KV[bi][1][0];
        const unsigned short* kr0 = kb + rdo0;
        const unsigned short* kr1 = kb + rdo1;
        const unsigned short* vr0 = vb + rdo0;
        const unsigned short* vr1 = vb + rdo1;

        f32x4 s0f[4], s1f[4];
#pragma unroll
        for (int f = 0; f < 4; f++) {
            s0f[f] = (f32x4){-16.f, -16.f, -16.f, -16.f};
            s1f[f] = (f32x4){-16.f, -16.f, -16.f, -16.f};
        }
        __builtin_amdgcn_s_setprio(1);
#pragma unroll
        for (int f = 0; f < 4; f++) {
            bf16x8 k0 = *reinterpret_cast<const bf16x8*>(kr0 + f * 1024);
            bf16x8 k1 = *reinterpret_cast<const bf16x8*>(kr1 + f * 1024);
            s0f[f] = __builtin_amdgcn_mfma_f32_16x16x32_bf16(k0, qf00, s0f[f], 0, 0, 0);
            s1f[f] = __builtin_amdgcn_mfma_f32_16x16x32_bf16(k0, qf10, s1f[f], 0, 0, 0);
            s0f[f] = __builtin_amdgcn_mfma_f32_16x16x32_bf16(k1, qf01, s0f[f], 0, 0, 0);
            s1f[f] = __builtin_amdgcn_mfma_f32_16x16x32_bf16(k1, qf11, s1f[f], 0, 0, 0);
        }
        __builtin_amdgcn_s_setprio(0);

        if (s0 + 63 > qb0) {   // causal mask, half 0
            const int qg = qb0 + c16;
#pragma unroll
            for (int f = 0; f < 4; f++)
#pragma unroll
                for (int r = 0; r < 4; r++)
                    if (s0 + f * 16 + g * 4 + r > qg) s0f[f][r] = -1e30f;
        }
        if (s0 + 63 > qb1) {   // causal mask, half 1
            const int qg = qb1 + c16;
#pragma unroll
            for (int f = 0; f < 4; f++)
#pragma unroll
                for (int r = 0; r < 4; r++)
                    if (s0 + f * 16 + g * 4 + r > qg) s1f[f][r] = -1e30f;
        }

        // half 0: exp2, pack to Ps, PV + l (skip if fully masked)
        if (s0 <= qb0 + 15) {
#pragma unroll
            for (int f = 0; f < 4; f++)
#pragma unroll
                for (int r = 0; r < 4; r++)
                    s0f[f][r] = __builtin_amdgcn_exp2f(s0f[f][r]);
#pragma unroll
            for (int f = 0; f < 4; f++) {
                u32x2 w;
                w[0] = pk2(s0f[f][0], s0f[f][1]);
                w[1] = pk2(s0f[f][2], s0f[f][3]);
                *reinterpret_cast<u32x2*>(pw[f]) = w;
            }
            __builtin_amdgcn_s_setprio(1);
#pragma unroll
            for (int ks = 0; ks < 2; ks++) {
                bf16x8 pa = *reinterpret_cast<const bf16x8*>(ks ? par1 : par0);
                const unsigned short* vp = ks ? vr1 : vr0;
                lac0 = __builtin_amdgcn_mfma_f32_16x16x32_bf16(ones, pa, lac0, 0, 0, 0);
#pragma unroll
                for (int fd = 0; fd < 4; fd++) {
                    bf16x8 vf = *reinterpret_cast<const bf16x8*>(vp + fd * 1024);
                    acc0[fd] = __builtin_amdgcn_mfma_f32_16x16x32_bf16(vf, pa, acc0[fd], 0, 0, 0);
                }
            }
            __builtin_amdgcn_s_setprio(0);
        }

        // half 1 (Ps reused; per-wave LDS ordering handles the WAR hazard)
        {
#pragma unroll
            for (int f = 0; f < 4; f++)
#pragma unroll
                for (int r = 0; r < 4; r++)
                    s1f[f][r] = __builtin_amdgcn_exp2f(s1f[f][r]);
#pragma unroll
            for (int f = 0; f < 4; f++) {
                u32x2 w;
                w[0] = pk2(s1f[f][0], s1f[f][1]);
                w[1] = pk2(s1f[f][2], s1f[f][3]);
                *reinterpret_cast<u32x2*>(pw[f]) = w;
            }
            __builtin_amdgcn_s_setprio(1);
#pragma unroll
            for (int ks = 0; ks < 2; ks++) {
                bf16x8 pa = *reinterpret_cast<const bf16x8*>(ks ? par1 : par0);
                const unsigned short* vp = ks ? vr1 : vr0;
                lac1 = __builtin_amdgcn_mfma_f32_16x16x32_bf16(ones, pa, lac1, 0, 0, 0);
#pragma unroll
                for (int fd = 0; fd < 4; fd++) {
                    bf16x8 vf = *reinterpret_cast<const bf16x8*>(vp + fd * 1024);
                    acc1[fd] = __builtin_amdgcn_mfma_f32_16x16x32_bf16(vf, pa, acc1[fd], 0, 0, 0);
                }
            }
            __builtin_amdgcn_s_setprio(0);
        }
    };

    // ---- 3-buffer, 2-deep pipeline with counted vmcnt ----
    stageTo(0, itlo << 6);
    if (itlo + 1 < ithi) stageTo(1, (itlo + 1) << 6);
    int bi = 0;
    for (int it = itlo; it < ithi; ++it) {
        if (it + 1 < ithi) { VM_WAIT4(); } else { VM_WAIT0(); }
        __builtin_amdgcn_s_barrier();
        if (it + 2 < ithi) stageTo(bi + 2 >= 3 ? bi - 1 : bi + 2, (it + 2) << 6);
        body(bi, it);
        bi = (bi + 1 == 3) ? 0 : bi + 1;
    }

    // epilogue: unnormalized partial O (bf16) + partial l (f32)
    unsigned short* op = split ? opB : opA;
#pragma unroll
    for (int fd = 0; fd < 4; fd++) {
        u32x2 w0, w1;
        w0[0] = pk2(acc0[fd][0], acc0[fd][1]);
        w0[1] = pk2(acc0[fd][2], acc0[fd][3]);
        w1[0] = pk2(acc1[fd][0], acc1[fd][1]);
        w1[1] = pk2(acc1[fd][2], acc1[fd][3]);
        const size_t c0 = ((size_t)b * T_ + qb0 + c16) * 1024 + h * 64 + fd * 16 + g * 4;
        const size_t c1 = ((size_t)b * T_ + qb1 + c16) * 1024 + h * 64 + fd * 16 + g * 4;
        *reinterpret_cast<u32x2*>(&op[c0]) = w0;
        *reinterpret_cast<u32x2*>(&op[c1]) = w1;
    }
    if (lane < 16) {
        const size_t base = (size_t)split * (B_ * H_ * T_) + ((size_t)(b * H_ + h)) * T_;
        lbuf[base + qb0 + c16] = lac0[0];
        lbuf[base + qb1 + c16] = lac1[0];
    }
}

// ---------------------------------------------------------------------------
// Kernel 2b (fused): bid<2048: y = (OA + OB) / (lA + lB); else wo-transpose.
// ---------------------------------------------------------------------------
__global__ __launch_bounds__(256) void combine_wo(
    const unsigned short* __restrict__ opA, const unsigned short* __restrict__ opB,
    const float* __restrict__ lbuf, unsigned short* __restrict__ y,
    const float* __restrict__ wo, unsigned short* __restrict__ wt)
{
    __shared__ unsigned short tile[64][72];
    const int bid = blockIdx.x, tid = threadIdx.x;
    if (bid < 2048) {
        const size_t i = ((size_t)bid * 256 + tid) * 8;
        const int hh = (int)((i >> 6) & 15);
        const int t = (int)((i >> 10) & 2047);
        const int bb = (int)(i >> 21);
        const size_t li = ((size_t)(bb * H_ + hh)) * T_ + t;
        const float inv = 1.0f / (lbuf[li] + lbuf[(size_t)B_ * H_ * T_ + li]);
        u16x8 a = *reinterpret_cast<const u16x8*>(opA + i);
        u16x8 c = *reinterpret_cast<const u16x8*>(opB + i);
        unsigned short o[8];
#pragma unroll
        for (int j = 0; j < 8; j++) o[j] = bf1((bf2f(a[j]) + bf2f(c[j])) * inv);
        *reinterpret_cast<u16x8*>(y + i) = *reinterpret_cast<u16x8*>(o);
    } else {
        const int wb2 = bid - 2048;
        const int tk = (wb2 & 15) << 6, tn = (wb2 >> 4) << 6;
        const int r = tid >> 2, cb = (tid & 3) << 4;
#pragma unroll
        for (int j = 0; j < 4; j++) {
            float4 v = *reinterpret_cast<const float4*>(
                wo + (size_t)(tk + r) * 1024 + tn + cb + j * 4);
            u32x2 w;
            w[0] = pk2(v.x, v.y);
            w[1] = pk2(v.z, v.w);
            *reinterpret_cast<u32x2*>(&tile[r][cb + j * 4]) = w;
        }
        __syncthreads();
        unsigned short buf[16];
#pragma unroll
        for (int j = 0; j < 16; j++) buf[j] = tile[cb + j][r];
        unsigned short* dst = wt + (size_t)(tn + r) * 1024 + tk + cb;
        *reinterpret_cast<u16x8*>(dst) = *reinterpret_cast<u16x8*>(buf);
        *reinterpret_cast<u16x8*>(dst + 8) = *reinterpret_cast<u16x8*>(buf + 8);
    }
}

// ---------------------------------------------------------------------------
// Kernel 3: out[4096,1024] = y(bf16) @ wt^T(bf16)
// m97 shape: 128x64 tiles (512 blocks), BK=32, single-buffer 12KB LDS.
// (left unchanged as control)
// ---------------------------------------------------------------------------
__global__ __launch_bounds__(256) void out_proj(
    const unsigned short* __restrict__ y, const unsigned short* __restrict__ wt,
    float* __restrict__ out)
{
    __shared__ __align__(16) unsigned short As[128 * 32];
    __shared__ __align__(16) unsigned short Bs[64 * 32];
    const int tid = threadIdx.x;
    const int lane = tid & 63, wave = tid >> 6;
    const int g = lane >> 4, c16 = lane & 15;
    const int xcd = blockIdx.x & 7, idx = blockIdx.x >> 3;   // 512 = 8 * (4 bm * 16 bn)
    const int bm = (xcd << 2) + (idx >> 4), bn = idx & 15;
    const int wm = (wave >> 1) << 6, wn = (wave & 1) << 5;

    const int srow = lane >> 2, sch = (lane & 3) << 3;
    const unsigned short* ysrc = y + ((size_t)(bm << 7) + wave * 32 + srow) * 1024 + sch;
    const unsigned short* wsrc = wt + ((size_t)(bn << 6) + wave * 16 + srow) * 1024 + sch;

    f32x4 acc[4][2];
#pragma unroll
    for (int i = 0; i < 4; i++)
#pragma unroll
        for (int j = 0; j < 2; j++) acc[i][j] = (f32x4){0.f, 0.f, 0.f, 0.f};

    for (int t = 0; t < 32; ++t) {
        const int k0 = t << 5;
        __syncthreads();
        gll16(ysrc + k0,             &As[(wave * 32) << 5]);
        gll16(ysrc + k0 + 16 * 1024, &As[(wave * 32 + 16) << 5]);
        gll16(wsrc + k0,             &Bs[(wave * 16) << 5]);
        __syncthreads();

        bf16x8 af[4], bfr[2];
#pragma unroll
        for (int m = 0; m < 4; m++)
            af[m] = *reinterpret_cast<const bf16x8*>(&As[((wm + m * 16 + c16) << 5) + g * 8]);
#pragma unroll
        for (int n = 0; n < 2; n++)
            bfr[n] = *reinterpret_cast<const bf16x8*>(&Bs[((wn + n * 16 + c16) << 5) + g * 8]);
#pragma unroll
        for (int m = 0; m < 4; m++)
#pragma unroll
            for (int n = 0; n < 2; n++)
                acc[m][n] = __builtin_amdgcn_mfma_f32_16x16x32_bf16(af[m], bfr[n], acc[m][n], 0, 0, 0);
    }

#pragma unroll
    for (int m = 0; m < 4; m++) {
        const int grow = (bm << 7) + wm + m * 16 + (g << 2);
#pragma unroll
        for (int n = 0; n < 2; n++) {
            const int gcol = (bn << 6) + wn + n * 16 + c16;
#pragma unroll
            for (int r = 0; r < 4; r++)
                out[(size_t)(grow + r) * 1024 + gcol] = acc[m][n][r];
        }
    }
}

extern "C" void kernel_launch(void* const* d_in, const int* in_sizes, int n_in,
                              void* d_out, int out_size, void* d_ws, size_t ws_size,
                              hipStream_t stream) {
    const float* x  = (const float*)d_in[0];
    const float* wq = (const float*)d_in[1];
    const float* wk = (const float*)d_in[2];
    const float* wv = (const float*)d_in[3];
    const float* wo = (const float*)d_in[4];
    float* out = (float*)d_out;

    // ws (32 MB): [0,6) wb -> [0,8) opB/y ; [8,32) qkv -> [8,10) wt
    // d_out (16 MB): [0,8) xb -> opA ; [8,8.5) lbuf ; out_proj overwrites all.
    unsigned short* wb   = (unsigned short*)d_ws;
    unsigned short* opB  = (unsigned short*)d_ws;
    unsigned short* y    = opB;
    unsigned short* qkv  = (unsigned short*)d_ws + (size_t)4 * 1024 * 1024;
    unsigned short* wt   = qkv;
    unsigned short* xb   = (unsigned short*)d_out;
    unsigned short* opA  = (unsigned short*)d_out;
    float* lbuf = (float*)((char*)d_out + (size_t)8 * 1024 * 1024);

    prep_all<<<dim3(1792), 256, 0, stream>>>(x, wq, wk, wv, xb, wb);
    qkv_gemm<<<dim3(768), 256, 0, stream>>>(xb, wb, qkv);
    attn<<<dim3(1024), 256, 0, stream>>>(qkv, opA, opB, lbuf);
    combine_wo<<<dim3(2048 + 256), 256, 0, stream>>>(opA, opB, lbuf, y, wo, wt);
    out_proj<<<dim3(512), 256, 0, stream>>>(y, wt, out);
}

// Round 16
// 107.458 us; speedup vs baseline: 1.0726x; 1.0726x over previous
//
#include <hip/hip_runtime.h>
#include <hip/hip_bf16.h>

#define B_ 2
#define T_ 2048
#define C_ 1024
#define H_ 16
#define D_ 64

typedef __attribute__((ext_vector_type(8))) short bf16x8;   // MFMA A/B operand (8 bf16)
typedef __attribute__((ext_vector_type(4))) float f32x4;    // MFMA C/D
typedef __attribute__((ext_vector_type(8))) unsigned short u16x8;
typedef __attribute__((ext_vector_type(2))) unsigned int u32x2;
typedef __attribute__((ext_vector_type(4))) unsigned int u32x4;

__device__ __forceinline__ unsigned short bf1(float a) {
    __bf16 x = (__bf16)a;
    return __builtin_bit_cast(unsigned short, x);
}
__device__ __forceinline__ unsigned int pk2(float a, float b) {
    return (unsigned int)bf1(a) | ((unsigned int)bf1(b) << 16);
}
__device__ __forceinline__ float bf2f(unsigned short u) {
    union { unsigned int u; float f; } v; v.u = (unsigned int)u << 16;
    return v.f;
}

__device__ __forceinline__ void gll16(const void* g, void* l) {
    __builtin_amdgcn_global_load_lds(
        (const __attribute__((address_space(1))) unsigned int*)g,
        (__attribute__((address_space(3))) unsigned int*)l, 16, 0, 0);
}

// ---------------------------------------------------------------------------
// Kernel 0: fused prep.  bid<1024: x f32->bf16 (xb). else: wq|wk|wv -> wb.
// ---------------------------------------------------------------------------
__global__ __launch_bounds__(256) void prep_all(
    const float* __restrict__ x, const float* __restrict__ wq,
    const float* __restrict__ wk, const float* __restrict__ wv,
    unsigned short* __restrict__ xb, unsigned short* __restrict__ wb)
{
    const int bid = blockIdx.x, tid = threadIdx.x;
    if (bid < 1024) {
        const size_t i = ((size_t)bid * 256 + tid) * 16;
        float4 f0 = *reinterpret_cast<const float4*>(x + i);
        float4 f1 = *reinterpret_cast<const float4*>(x + i + 4);
        float4 f2 = *reinterpret_cast<const float4*>(x + i + 8);
        float4 f3 = *reinterpret_cast<const float4*>(x + i + 12);
        u32x4 a = {pk2(f0.x, f0.y), pk2(f0.z, f0.w), pk2(f1.x, f1.y), pk2(f1.z, f1.w)};
        u32x4 b = {pk2(f2.x, f2.y), pk2(f2.z, f2.w), pk2(f3.x, f3.y), pk2(f3.z, f3.w)};
        *reinterpret_cast<u32x4*>(xb + i) = a;
        *reinterpret_cast<u32x4*>(xb + i + 8) = b;
    } else {
        const int rb = (bid - 1024) * 4;
        const float* src = (rb < 1024) ? wq + (size_t)rb * 1024
                         : (rb < 2048) ? wk + (size_t)(rb - 1024) * 1024
                                       : wv + (size_t)(rb - 2048) * 1024;
        const float sc = (rb < 1024) ? 0.125f * 1.4426950408889634f : 1.0f;
        const float4* s4 = (const float4*)src;
        u32x2* d = (u32x2*)(wb + (size_t)rb * 1024);
#pragma unroll
        for (int k = 0; k < 4; k++) {
            float4 v = s4[k * 256 + tid];
            u32x2 w;
            w[0] = pk2(v.x * sc, v.y * sc);
            w[1] = pk2(v.z * sc, v.w * sc);
            d[k * 256 + tid] = w;
        }
    }
}

// ---------------------------------------------------------------------------
// Kernel 1: qkv GEMM.  Z[4096,3072] = xb[4096,1024](bf16) * wb^T(bf16)
// m97 shape: BK=32, single-buffer 16KB LDS, both operands via gll16.
// Q,K written [b][h][t][d]; V written TRANSPOSED: vT[b][h][d][t].
// ---------------------------------------------------------------------------
__global__ __launch_bounds__(256) void qkv_gemm(
    const unsigned short* __restrict__ xb, const unsigned short* __restrict__ wb,
    unsigned short* __restrict__ qkv)
{
    __shared__ __align__(16) unsigned short As[128 * 32];
    __shared__ __align__(16) unsigned short Bs[128 * 32];
    const int tid = threadIdx.x;
    const int lane = tid & 63, wave = tid >> 6;
    const int g = lane >> 4, c16 = lane & 15;
    const int xcd = blockIdx.x & 7, idx = blockIdx.x >> 3;
    const int bm = (xcd << 2) + idx / 24, bn = idx % 24;
    const int jbase = bn << 7;
    const int which = jbase >> 10;

    const int srow = lane >> 2, sch = (lane & 3) << 3;
    const unsigned short* asrc = xb + ((size_t)(bm << 7) + wave * 32 + srow) * C_ + sch;
    const unsigned short* bsrc = wb + ((size_t)(bn << 7) + wave * 32 + srow) * C_ + sch;

    f32x4 acc[4][4];
#pragma unroll
    for (int i = 0; i < 4; i++)
#pragma unroll
        for (int j = 0; j < 4; j++) acc[i][j] = (f32x4){0.f, 0.f, 0.f, 0.f};

    const int wm = (wave >> 1) << 6, wn = (wave & 1) << 6;

    for (int t = 0; t < 32; ++t) {
        const int k0 = t << 5;
        __syncthreads();
        gll16(asrc + k0,           &As[(wave * 32) << 5]);
        gll16(asrc + k0 + 16 * C_, &As[(wave * 32 + 16) << 5]);
        gll16(bsrc + k0,           &Bs[(wave * 32) << 5]);
        gll16(bsrc + k0 + 16 * C_, &Bs[(wave * 32 + 16) << 5]);
        __syncthreads();

        bf16x8 af[4], bfv[4];
#pragma unroll
        for (int m = 0; m < 4; m++)
            af[m] = *reinterpret_cast<const bf16x8*>(&As[((wm + m * 16 + c16) << 5) + g * 8]);
#pragma unroll
        for (int n = 0; n < 4; n++)
            bfv[n] = *reinterpret_cast<const bf16x8*>(&Bs[((wn + n * 16 + c16) << 5) + g * 8]);
#pragma unroll
        for (int m = 0; m < 4; m++)
#pragma unroll
            for (int n = 0; n < 4; n++)
                acc[m][n] = __builtin_amdgcn_mfma_f32_16x16x32_bf16(af[m], bfv[n], acc[m][n], 0, 0, 0);
    }

    if (which < 2) {
#pragma unroll
        for (int m = 0; m < 4; m++) {
            const int grow = (bm << 7) + wm + m * 16 + (g << 2);
#pragma unroll
            for (int n = 0; n < 4; n++) {
                const int jj = (jbase + wn + n * 16 + c16) & 1023;
                const int h = jj >> 6, d = jj & 63;
#pragma unroll
                for (int r = 0; r < 4; r++) {
                    const int row = grow + r;
                    const int b = row >> 11, t = row & 2047;
                    const size_t off = ((size_t)((which * B_ + b) * H_ + h) * T_ + t) * 64 + d;
                    qkv[off] = bf1(acc[m][n][r]);
                }
            }
        }
    } else {
        // V transposed: vT[b][h][d][t]
#pragma unroll
        for (int m = 0; m < 4; m++) {
            const int grow = (bm << 7) + wm + m * 16 + (g << 2);
            const int b = grow >> 11, t = grow & 2047;
#pragma unroll
            for (int n = 0; n < 4; n++) {
                const int jj = (jbase + wn + n * 16 + c16) & 1023;
                const int h = jj >> 6, d = jj & 63;
                u32x2 w;
                w[0] = pk2(acc[m][n][0], acc[m][n][1]);
                w[1] = pk2(acc[m][n][2], acc[m][n][3]);
                const size_t off = ((size_t)((2 * B_ + b) * H_ + h) * 64 + d) * T_ + t;
                *reinterpret_cast<u32x2*>(&qkv[off]) = w;
            }
        }
    }
}

// ---------------------------------------------------------------------------
// Kernel 2: causal flash attention, STATIC-MAX softmax, QBLK=64.
// 24 KB LDS (single-buffered K/V + Ps) -> 6 blocks/CU co-resident: inter-block
// wave overlap hides barrier drains + MFMA latency (the qkv_gemm mechanism).
// Grid 2048 (longest-first, 2-way kv-split); l on MFMA pipe (ones row).
// ---------------------------------------------------------------------------
__global__ __launch_bounds__(256) void attn(
    const unsigned short* __restrict__ qkv,
    unsigned short* __restrict__ opA, unsigned short* __restrict__ opB,
    float* __restrict__ lbuf)
{
    __shared__ __align__(16) unsigned short Ks[64 * 64];
    __shared__ __align__(16) unsigned short Vt[64 * 64];
    __shared__ __align__(16) unsigned short Ps[4][16 * 64];
    const int tid = threadIdx.x, lane = tid & 63, wave = tid >> 6;
    const int g = lane >> 4, c16 = lane & 15;
    const int qt = 31 - (blockIdx.x >> 6);     // longest first
    const int rem = blockIdx.x & 63;
    const int half = rem >> 5, bh = rem & 31;
    const int b = bh >> 4, h = bh & 15;
    const size_t headoff = (size_t)(b * H_ + h) * T_ * 64;
    const size_t QSZ = (size_t)B_ * H_ * T_ * 64;
    const unsigned short* qp = qkv + headoff;
    const unsigned short* kp = qkv + QSZ + headoff;
    const unsigned short* vTp = qkv + 2 * QSZ + headoff;   // [d][t]

    const int nt = qt + 1;
    const int h1 = (nt + 1) >> 1;
    const int itlo = half ? h1 : 0, ithi = half ? nt : h1;

    const int qb = (qt << 6) + wave * 16;
    bf16x8 qf0, qf1;
    {
        const size_t r0 = (size_t)(qb + c16) * 64;
        qf0 = *reinterpret_cast<const bf16x8*>(qp + r0 + g * 8);
        qf1 = *reinterpret_cast<const bf16x8*>(qp + r0 + 32 + g * 8);
    }

    const bf16x8 ones = {0x3F80, 0x3F80, 0x3F80, 0x3F80, 0x3F80, 0x3F80, 0x3F80, 0x3F80};
    f32x4 lacc = (f32x4){0.f, 0.f, 0.f, 0.f};
    f32x4 acc[4];
#pragma unroll
    for (int i = 0; i < 4; i++) acc[i] = (f32x4){0.f, 0.f, 0.f, 0.f};

    // ---- loop-invariant LDS pointers ----
    const int sw = c16 & 7;
    const int rdo0 = (c16 << 6) + ((g ^ sw) << 3);         // chunk g
    const int rdo1 = (c16 << 6) + (((g + 4) ^ sw) << 3);   // chunk g+4
    const unsigned short* kr0 = Ks + rdo0;
    const unsigned short* kr1 = Ks + rdo1;
    const unsigned short* vr0 = Vt + rdo0;
    const unsigned short* vr1 = Vt + rdo1;
    const unsigned short* par0 = Ps[wave] + rdo0;
    const unsigned short* par1 = Ps[wave] + rdo1;
    unsigned short* pw[4];
#pragma unroll
    for (int f = 0; f < 4; f++)
        pw[f] = Ps[wave] + (c16 << 6)
              + (((((f << 1) + (g >> 1))) ^ sw) << 3) + ((g & 1) << 2);

    // ---- staging (pre-swizzled global source, linear LDS dest, rule 21) ----
    const int srow8 = lane >> 3;
    const int swc = ((lane & 7) ^ srow8) << 3;
    const unsigned short* ksrc = kp + (size_t)(wave * 16 + srow8) * 64 + swc;
    const unsigned short* vsrc = vTp + (size_t)(wave * 16 + srow8) * T_ + swc;

    for (int it = itlo; it < ithi; ++it) {
        const int s0 = it << 6;
        __syncthreads();                       // prev body done reading K/V
#pragma unroll
        for (int i = 0; i < 2; i++) {
            gll16(ksrc + (size_t)(s0 + i * 8) * 64, &Ks[(wave * 16 + i * 8) << 6]);
            gll16(vsrc + s0 + (size_t)i * 8 * T_, &Vt[(wave * 16 + i * 8) << 6]);
        }
        __syncthreads();                       // stage complete (vmcnt drained)

        // S^T[kv][q] = K · Q^T, C-init = -16 (static-max bias, free)
        f32x4 sfT[4];
#pragma unroll
        for (int f = 0; f < 4; f++) sfT[f] = (f32x4){-16.f, -16.f, -16.f, -16.f};
        __builtin_amdgcn_s_setprio(1);
#pragma unroll
        for (int f = 0; f < 4; f++) {
            bf16x8 k0 = *reinterpret_cast<const bf16x8*>(kr0 + f * 1024);
            bf16x8 k1 = *reinterpret_cast<const bf16x8*>(kr1 + f * 1024);
            sfT[f] = __builtin_amdgcn_mfma_f32_16x16x32_bf16(k0, qf0, sfT[f], 0, 0, 0);
            sfT[f] = __builtin_amdgcn_mfma_f32_16x16x32_bf16(k1, qf1, sfT[f], 0, 0, 0);
        }
        __builtin_amdgcn_s_setprio(0);

        if (it == qt) {   // diagonal tile: causal mask
            const int qg = qb + c16;
#pragma unroll
            for (int f = 0; f < 4; f++)
#pragma unroll
                for (int r = 0; r < 4; r++) {
                    const int kv = s0 + f * 16 + g * 4 + r;
                    if (kv > qg) sfT[f][r] = -1e30f;
                }
        }

        // static-max softmax: P = 2^sfT
#pragma unroll
        for (int f = 0; f < 4; f++)
#pragma unroll
            for (int r = 0; r < 4; r++)
                sfT[f][r] = __builtin_amdgcn_exp2f(sfT[f][r]);

        // P -> Ps (XOR-chunk swizzled)
#pragma unroll
        for (int f = 0; f < 4; f++) {
            u32x2 w;
            w[0] = pk2(sfT[f][0], sfT[f][1]);
            w[1] = pk2(sfT[f][2], sfT[f][3]);
            *reinterpret_cast<u32x2*>(pw[f]) = w;
        }

        // O^T += V^T · P ; l += ones · P  (both on the MFMA pipe)
        __builtin_amdgcn_s_setprio(1);
#pragma unroll
        for (int ks = 0; ks < 2; ks++) {
            bf16x8 pa = *reinterpret_cast<const bf16x8*>(ks ? par1 : par0);
            const unsigned short* vp = ks ? vr1 : vr0;
            lacc = __builtin_amdgcn_mfma_f32_16x16x32_bf16(ones, pa, lacc, 0, 0, 0);
#pragma unroll
            for (int fd = 0; fd < 4; fd++) {
                bf16x8 vf = *reinterpret_cast<const bf16x8*>(vp + fd * 1024);
                acc[fd] = __builtin_amdgcn_mfma_f32_16x16x32_bf16(vf, pa, acc[fd], 0, 0, 0);
            }
        }
        __builtin_amdgcn_s_setprio(0);
    }

    // epilogue: unnormalized partial O (bf16) + partial l (f32)
    unsigned short* op = half ? opB : opA;
#pragma unroll
    for (int fd = 0; fd < 4; fd++) {
        u32x2 w;
        w[0] = pk2(acc[fd][0], acc[fd][1]);
        w[1] = pk2(acc[fd][2], acc[fd][3]);
        const size_t cy = ((size_t)b * T_ + qb + c16) * 1024 + h * 64 + fd * 16 + g * 4;
        *reinterpret_cast<u32x2*>(&op[cy]) = w;
    }
    if (lane < 16)
        lbuf[(size_t)half * (B_ * H_ * T_) + ((size_t)(b * H_ + h)) * T_ + qb + c16] = lacc[0];
}

// ---------------------------------------------------------------------------
// Kernel 2b (fused): bid<2048: y = (OA + OB) / (lA + lB); else wo-transpose.
// ---------------------------------------------------------------------------
__global__ __launch_bounds__(256) void combine_wo(
    const unsigned short* __restrict__ opA, const unsigned short* __restrict__ opB,
    const float* __restrict__ lbuf, unsigned short* __restrict__ y,
    const float* __restrict__ wo, unsigned short* __restrict__ wt)
{
    __shared__ unsigned short tile[64][72];
    const int bid = blockIdx.x, tid = threadIdx.x;
    if (bid < 2048) {
        const size_t i = ((size_t)bid * 256 + tid) * 8;
        const int hh = (int)((i >> 6) & 15);
        const int t = (int)((i >> 10) & 2047);
        const int bb = (int)(i >> 21);
        const size_t li = ((size_t)(bb * H_ + hh)) * T_ + t;
        const float inv = 1.0f / (lbuf[li] + lbuf[(size_t)B_ * H_ * T_ + li]);
        u16x8 a = *reinterpret_cast<const u16x8*>(opA + i);
        u16x8 c = *reinterpret_cast<const u16x8*>(opB + i);
        unsigned short o[8];
#pragma unroll
        for (int j = 0; j < 8; j++) o[j] = bf1((bf2f(a[j]) + bf2f(c[j])) * inv);
        *reinterpret_cast<u16x8*>(y + i) = *reinterpret_cast<u16x8*>(o);
    } else {
        const int wb2 = bid - 2048;
        const int tk = (wb2 & 15) << 6, tn = (wb2 >> 4) << 6;
        const int r = tid >> 2, cb = (tid & 3) << 4;
#pragma unroll
        for (int j = 0; j < 4; j++) {
            float4 v = *reinterpret_cast<const float4*>(
                wo + (size_t)(tk + r) * 1024 + tn + cb + j * 4);
            u32x2 w;
            w[0] = pk2(v.x, v.y);
            w[1] = pk2(v.z, v.w);
            *reinterpret_cast<u32x2*>(&tile[r][cb + j * 4]) = w;
        }
        __syncthreads();
        unsigned short buf[16];
#pragma unroll
        for (int j = 0; j < 16; j++) buf[j] = tile[cb + j][r];
        unsigned short* dst = wt + (size_t)(tn + r) * 1024 + tk + cb;
        *reinterpret_cast<u16x8*>(dst) = *reinterpret_cast<u16x8*>(buf);
        *reinterpret_cast<u16x8*>(dst + 8) = *reinterpret_cast<u16x8*>(buf + 8);
    }
}

// ---------------------------------------------------------------------------
// Kernel 3: out[4096,1024] = y(bf16) @ wt^T(bf16)
// m97 shape: 128x64 tiles (512 blocks), BK=32, single-buffer 12KB LDS.
// ---------------------------------------------------------------------------
__global__ __launch_bounds__(256) void out_proj(
    const unsigned short* __restrict__ y, const unsigned short* __restrict__ wt,
    float* __restrict__ out)
{
    __shared__ __align__(16) unsigned short As[128 * 32];
    __shared__ __align__(16) unsigned short Bs[64 * 32];
    const int tid = threadIdx.x;
    const int lane = tid & 63, wave = tid >> 6;
    const int g = lane >> 4, c16 = lane & 15;
    const int xcd = blockIdx.x & 7, idx = blockIdx.x >> 3;   // 512 = 8 * (4 bm * 16 bn)
    const int bm = (xcd << 2) + (idx >> 4), bn = idx & 15;
    const int wm = (wave >> 1) << 6, wn = (wave & 1) << 5;

    const int srow = lane >> 2, sch = (lane & 3) << 3;
    const unsigned short* ysrc = y + ((size_t)(bm << 7) + wave * 32 + srow) * 1024 + sch;
    const unsigned short* wsrc = wt + ((size_t)(bn << 6) + wave * 16 + srow) * 1024 + sch;

    f32x4 acc[4][2];
#pragma unroll
    for (int i = 0; i < 4; i++)
#pragma unroll
        for (int j = 0; j < 2; j++) acc[i][j] = (f32x4){0.f, 0.f, 0.f, 0.f};

    for (int t = 0; t < 32; ++t) {
        const int k0 = t << 5;
        __syncthreads();
        gll16(ysrc + k0,             &As[(wave * 32) << 5]);
        gll16(ysrc + k0 + 16 * 1024, &As[(wave * 32 + 16) << 5]);
        gll16(wsrc + k0,             &Bs[(wave * 16) << 5]);
        __syncthreads();

        bf16x8 af[4], bfr[2];
#pragma unroll
        for (int m = 0; m < 4; m++)
            af[m] = *reinterpret_cast<const bf16x8*>(&As[((wm + m * 16 + c16) << 5) + g * 8]);
#pragma unroll
        for (int n = 0; n < 2; n++)
            bfr[n] = *reinterpret_cast<const bf16x8*>(&Bs[((wn + n * 16 + c16) << 5) + g * 8]);
#pragma unroll
        for (int m = 0; m < 4; m++)
#pragma unroll
            for (int n = 0; n < 2; n++)
                acc[m][n] = __builtin_amdgcn_mfma_f32_16x16x32_bf16(af[m], bfr[n], acc[m][n], 0, 0, 0);
    }

#pragma unroll
    for (int m = 0; m < 4; m++) {
        const int grow = (bm << 7) + wm + m * 16 + (g << 2);
#pragma unroll
        for (int n = 0; n < 2; n++) {
            const int gcol = (bn << 6) + wn + n * 16 + c16;
#pragma unroll
            for (int r = 0; r < 4; r++)
                out[(size_t)(grow + r) * 1024 + gcol] = acc[m][n][r];
        }
    }
}

extern "C" void kernel_launch(void* const* d_in, const int* in_sizes, int n_in,
                              void* d_out, int out_size, void* d_ws, size_t ws_size,
                              hipStream_t stream) {
    const float* x  = (const float*)d_in[0];
    const float* wq = (const float*)d_in[1];
    const float* wk = (const float*)d_in[2];
    const float* wv = (const float*)d_in[3];
    const float* wo = (const float*)d_in[4];
    float* out = (float*)d_out;

    // ws (32 MB): [0,6) wb -> [0,8) opB/y ; [8,32) qkv -> [8,10) wt
    // d_out (16 MB): [0,8) xb -> opA ; [8,8.5) lbuf ; out_proj overwrites all.
    unsigned short* wb   = (unsigned short*)d_ws;
    unsigned short* opB  = (unsigned short*)d_ws;
    unsigned short* y    = opB;
    unsigned short* qkv  = (unsigned short*)d_ws + (size_t)4 * 1024 * 1024;
    unsigned short* wt   = qkv;
    unsigned short* xb   = (unsigned short*)d_out;
    unsigned short* opA  = (unsigned short*)d_out;
    float* lbuf = (float*)((char*)d_out + (size_t)8 * 1024 * 1024);

    prep_all<<<dim3(1792), 256, 0, stream>>>(x, wq, wk, wv, xb, wb);
    qkv_gemm<<<dim3(768), 256, 0, stream>>>(xb, wb, qkv);
    attn<<<dim3(2048), 256, 0, stream>>>(qkv, opA, opB, lbuf);
    combine_wo<<<dim3(2048 + 256), 256, 0, stream>>>(opA, opB, lbuf, y, wo, wt);
    out_proj<<<dim3(512), 256, 0, stream>>>(y, wt, out);
}